// Round 10
// baseline (81.028 us; speedup 1.0000x reference)
//
#include <hip/hip_runtime.h>
#include <stdint.h>

// HierarchicalZ2_12Quantizer on MI355X (gfx950) — barrier-free per-wave pipeline.
// tokens = 8*4096 = 32768, D = 1024
// R9 post-mortem: 3.3 TB/s aggregate (53% of achievable) — phase convoy:
// __syncthreads forced all waves through read-only / VALU-only / write phases
// in lockstep. R10: quantize made wave-local (roles split across LANE GROUPS,
// 16 tokens x 4 roles = 64 lanes), gate scales via shuffle -> ZERO barriers.
// 8 independent waves/CU drift -> reads+writes mix -> bidirectional HBM.
// Per-wave LDS (16KB): down dbuf [0,16K) / epi xe dbuf [0,8K), C [8K,12.5K),
// P [12.5K,14.7K), V16 [14.7K,16K) (C overlaps dead P/V only after use).
// codes from bit patterns: c[j][i] = ((j>>(n-1-i))&1)?+1:-1.

#define DM 1024
#define TPB 64
#define OUT_OFF ((size_t)33554432)  // 8*4096*1024
#define NTOK 32768
#define NSLOT 32
#define WSA_OFF 32768               // float offset of gate-acc in ws

typedef float f32x4 __attribute__((ext_vector_type(4)));
typedef short bf16x8 __attribute__((ext_vector_type(8)));

typedef const __attribute__((address_space(1))) unsigned int* gas1_t;
typedef __attribute__((address_space(3))) unsigned int* las3_t;

__device__ __forceinline__ void gl_lds16(const void* g, void* l){
  __builtin_amdgcn_global_load_lds((gas1_t)g, (las3_t)l, 16, 0, 0);
}

__device__ __forceinline__ short f2bf(float f){
  unsigned u = __builtin_bit_cast(unsigned, f);
  unsigned r = u + 0x7fffu + ((u >> 16) & 1u);   // round-to-nearest-even
  return (short)(r >> 16);
}

// soft_quantize over the 2^NB hypercube corners; z[NB] -> q[NB]
template<int NB>
__device__ __forceinline__ void softq(const float* z, float invt, float* q){
  constexpr int K = 1 << NB;
  float d[K];
  float dmin = 3.4e38f;
#pragma unroll
  for (int j = 0; j < K; ++j){
    float acc = 0.f;
#pragma unroll
    for (int i = 0; i < NB; ++i){
      float c = ((j >> (NB-1-i)) & 1) ? 1.f : -1.f;
      float t = z[i] - c;
      acc = fmaf(t, t, acc);
    }
    float dj = sqrtf(acc);
    d[j] = dj;
    dmin = fminf(dmin, dj);
  }
  float S = 0.f;
  float s1[NB];
#pragma unroll
  for (int i = 0; i < NB; ++i) s1[i] = 0.f;
#pragma unroll
  for (int j = 0; j < K; ++j){
    float wj = __expf((dmin - d[j]) * invt);
    S += wj;
#pragma unroll
    for (int i = 0; i < NB; ++i)
      if ((j >> (NB-1-i)) & 1) s1[i] += wj;   // compile-time bit -> no branch
  }
  float rS = 1.f / S;
#pragma unroll
  for (int i = 0; i < NB; ++i) q[i] = 2.f * s1[i] * rS - 1.f;  // (S1-S0)/S
}

// ---------------- pack: weights -> bf16 B-fragments in ws (once) ------------
// wsF[0..32768)      : W24 frags, 32 ksteps x 2 nfrags x 64 lanes x 8
// wsF[32768..57344)  : Wf compact frags, 64 dfrags x 48 lanes x 8 (k<24)
__global__ __launch_bounds__(256) void pack_kernel(
    const float* __restrict__ w_to_l1,  const float* __restrict__ w_to_l2,
    const float* __restrict__ w_to_l3u, const float* __restrict__ w_to_l3l,
    const float* __restrict__ w_gate,
    const float* __restrict__ w_from_l1, const float* __restrict__ w_from_l2,
    const float* __restrict__ w_from_l3,
    short* __restrict__ wsF, float* __restrict__ wsA)
{
  int base = blockIdx.x*4096 + threadIdx.x*16;
#pragma unroll
  for (int q = 0; q < 16; ++q){
    int e = base + q;
    float v;
    if (e < 32768){
      int s  = e >> 10;
      int nf = (e >> 9) & 1;
      int ll = (e >> 3) & 63;
      int j  = e & 7;
      int k  = s*32 + ((ll >> 4) << 3) + j;
      int n  = nf*16 + (ll & 15);
      if      (n < 3)  v = w_gate  [k*3 + n];
      else if (n < 6)  v = w_to_l1 [k*3 + (n-3)];
      else if (n < 12) v = w_to_l2 [k*6 + (n-6)];
      else if (n < 18) v = w_to_l3u[k*6 + (n-12)];
      else if (n < 24) v = w_to_l3l[k*6 + (n-18)];
      else             v = 0.f;
    } else {
      int e2  = e - 32768;
      int f   = e2 / 384;
      int rem = e2 - f*384;
      int ll  = rem >> 3;
      int j   = e2 & 7;
      int k   = ((ll >> 4) << 3) + j;      // 0..23
      int dd  = f*16 + (ll & 15);
      if      (k < 3)  v = w_from_l1[k*DM + dd];
      else if (k < 9)  v = w_from_l2[(k-3)*DM + dd];
      else if (k < 21) v = w_from_l3[(k-9)*DM + dd];
      else             v = 0.f;
    }
    wsF[e] = f2bf(v);
  }
  if (blockIdx.x == 0){
    wsA[threadIdx.x]       = 0.f;
    wsA[threadIdx.x + 256] = 0.f;
  }
}

// ---------------- fused: barrier-free per-wave down+quantize+up+residual ----
__global__ __launch_bounds__(256, 2) void hq8_kernel(
    const float* __restrict__ x, const short* __restrict__ wsF,
    const float* __restrict__ b_gate,
    const float* __restrict__ t1p, const float* __restrict__ t2p, const float* __restrict__ t3p,
    const float* __restrict__ s1p, const float* __restrict__ s2p, const float* __restrict__ s3p,
    float* __restrict__ wsA, float* __restrict__ out)
{
  // 16 KB strictly per-wave; NO cross-wave LDS, NO __syncthreads anywhere.
  __shared__ alignas(16) char smem[65536];

  const int tid  = threadIdx.x;
  const int l    = tid & 63;
  const int wv   = tid >> 6;    // wave 0..3, owns tokens [wv*16, wv*16+16)
  const int kg   = l >> 4;
  const int ln16 = l & 15;
  const int tokBase = blockIdx.x * TPB + wv*16;

  char*  W  = smem + wv*16384;
  float* Cw = reinterpret_cast<float*>(W + 8192);    // [16][68] f32 (epi)
  float* Pw = reinterpret_cast<float*>(W + 12544);   // [16][34] f32
  short* Vw = reinterpret_cast<short*>(W + 14720);   // [16][40] bf16

  // preload ALL scalar params before any counted vmcnt sequence
  const float invt1 = 1.f / fminf(fmaxf(__expf(t1p[0]), 0.01f), 5.0f);
  const float invt2 = 1.f / fminf(fmaxf(__expf(t2p[0]), 0.01f), 5.0f);
  const float invt3 = 1.f / fminf(fmaxf(__expf(t3p[0]), 0.01f), 5.0f);
  const float s1v = s1p[0], s2v = s2p[0], s3v = s3p[0];
  const float bg0 = b_gate[0], bg1 = b_gate[1], bg2 = b_gate[2];

  // ================= down-proj: Pw = x @ W24 (per-wave, dbuf DMA) ===========
  {
    f32x4 acc0 = {0.f,0.f,0.f,0.f}, acc1 = {0.f,0.f,0.f,0.f};
    const int lr0 = l >> 5;     // 0/1
    const int cbp = l & 31;     // 16B-block within 512B row
#pragma unroll
    for (int i = 0; i < 8; ++i){
      int lr = i*2 + lr0;
      gl_lds16(x + (size_t)(tokBase + lr)*DM + (cbp ^ (lr & 7))*4,
               W + i*1024 + l*16);
    }
#pragma unroll
    for (int t = 0; t < 8; ++t){
      const int buf = t & 1;
      bf16x8 bfr[8];
#pragma unroll
      for (int s2 = 0; s2 < 8; ++s2)
        bfr[s2] = *reinterpret_cast<const bf16x8*>(&wsF[(t*8 + s2)*512 + l*8]);
      __builtin_amdgcn_sched_barrier(0);
      if (t < 7){
#pragma unroll
        for (int i = 0; i < 8; ++i){
          int lr = i*2 + lr0;
          gl_lds16(x + (size_t)(tokBase + lr)*DM + (t+1)*128 + (cbp ^ (lr & 7))*4,
                   W + (buf^1)*8192 + i*1024 + l*16);
        }
        asm volatile("s_waitcnt vmcnt(8)" ::: "memory");
      } else {
        asm volatile("s_waitcnt vmcnt(0)" ::: "memory");
      }
      const char* abase = W + buf*8192 + ln16*512;
#pragma unroll
      for (int s = 0; s < 4; ++s){
        float4 xa = *reinterpret_cast<const float4*>(abase + ((s*8 + kg*2 + 0) ^ (ln16 & 7))*16);
        float4 xb = *reinterpret_cast<const float4*>(abase + ((s*8 + kg*2 + 1) ^ (ln16 & 7))*16);
        bf16x8 af;
        af[0]=f2bf(xa.x); af[1]=f2bf(xa.y); af[2]=f2bf(xa.z); af[3]=f2bf(xa.w);
        af[4]=f2bf(xb.x); af[5]=f2bf(xb.y); af[6]=f2bf(xb.z); af[7]=f2bf(xb.w);
        acc0 = __builtin_amdgcn_mfma_f32_16x16x32_bf16(af, bfr[s*2+0], acc0, 0, 0, 0);
        acc1 = __builtin_amdgcn_mfma_f32_16x16x32_bf16(af, bfr[s*2+1], acc1, 0, 0, 0);
      }
    }
#pragma unroll
    for (int r = 0; r < 4; ++r){      // D: col = l&15, row(token) = kg*4 + r
      int row = kg*4 + r;
      Pw[row*34 + ln16]      = acc0[r];
      Pw[row*34 + 16 + ln16] = acc1[r];
    }
  }

  // ---- epi prologue: D(0)->xe buf0, bw(0) frags, D(1)->xe buf1 -------------
  const short* wsFC = wsF + 32768;
  bf16x8 bwc0={0,0,0,0,0,0,0,0}, bwc1=bwc0, bwc2=bwc0, bwc3=bwc0;
  {
#pragma unroll
    for (int j = 0; j < 4; ++j){
      int lr = j*4 + (l >> 4);
      gl_lds16(x + (size_t)(tokBase + lr)*DM + ((l & 15) ^ (lr & 7))*4,
               W + j*1024 + l*16);
    }
    if (kg < 3){
      bwc0 = *reinterpret_cast<const bf16x8*>(&wsFC[0*384 + l*8]);
      bwc1 = *reinterpret_cast<const bf16x8*>(&wsFC[1*384 + l*8]);
      bwc2 = *reinterpret_cast<const bf16x8*>(&wsFC[2*384 + l*8]);
      bwc3 = *reinterpret_cast<const bf16x8*>(&wsFC[3*384 + l*8]);
    }
#pragma unroll
    for (int j = 0; j < 4; ++j){
      int lr = j*4 + (l >> 4);
      gl_lds16(x + (size_t)(tokBase + lr)*DM + 64 + ((l & 15) ^ (lr & 7))*4,
               W + 4096 + j*1024 + l*16);
    }
  }

  // ================= quantize: wave-local; lane group = role ================
  // gi 0: l2 (cols 6-11), 1: l3u (12-17), 2: l3l (18-23), 3: gate+l1 (0-5)
  float qv[6] = {0,0,0,0,0,0};
  float myscale = 0.f, g1s2v = 0.f, g2s3v = 0.f;
  float sg0 = 0.f, sg1 = 0.f, sg2 = 0.f;
  {
    const int t  = ln16;
    const int gi = kg;
    const int base = (gi == 3) ? 0 : 6 + gi*6;
    float z[6];
#pragma unroll
    for (int i = 0; i < 6; ++i) z[i] = Pw[t*34 + base + i];
    if (gi == 3){
      float g0l = z[0] + bg0;
      float g1l = z[1] + bg1;
      float g2l = z[2] + bg2;
      float m  = fmaxf(g0l, fmaxf(g1l, g2l));
      float e0 = __expf(g0l - m), e1 = __expf(g1l - m), e2 = __expf(g2l - m);
      float rs = 1.f / (e0 + e1 + e2);
      float g0 = e0*rs, g1 = e1*rs, g2 = e2*rs;
      myscale = g0 * s1v;
      g1s2v   = g1 * s2v;
      g2s3v   = g2 * s3v;
      float z1[3] = {z[3], z[4], z[5]};
      softq<3>(z1, invt1, qv);
      sg0 = g0; sg1 = g1; sg2 = g2;     // reduce over the 16 gate lanes
#pragma unroll
      for (int mm = 1; mm < 16; mm <<= 1){
        sg0 += __shfl_xor(sg0, mm, 64);
        sg1 += __shfl_xor(sg1, mm, 64);
        sg2 += __shfl_xor(sg2, mm, 64);
      }
    } else {
      float invt = (gi == 0) ? invt2 : invt3;
      softq<6>(z, invt, qv);
    }
    // gate scales to the other lane groups via shuffle (no LDS, no barrier)
    float gs1 = __shfl(g1s2v, 48 + t, 64);
    float gs2 = __shfl(g2s3v, 48 + t, 64);
    // V writes (gate-scaled bf16): l1 0-2, l2 3-8, l3u 9-14, l3l 15-20
    if (gi == 3){
#pragma unroll
      for (int i = 0; i < 3; ++i) Vw[t*40 + i] = f2bf(myscale * qv[i]);
      Vw[t*40 + 21] = 0; Vw[t*40 + 22] = 0; Vw[t*40 + 23] = 0;  // kg=2 tail
    } else {
      float sc = (gi == 0) ? gs1 : gs2;
      int voff = 3 + gi*6;
#pragma unroll
      for (int i = 0; i < 6; ++i) Vw[t*40 + voff + i] = f2bf(sc * qv[i]);
    }
  }

  // ================= up-proj + residual, 16 col-chunks of 64 (per-wave) =====
  bf16x8 aV = {0,0,0,0,0,0,0,0};
  if (kg < 3)
    aV = *reinterpret_cast<const bf16x8*>(&Vw[ln16*40 + kg*8]);
  const f32x4 z4 = {0.f,0.f,0.f,0.f};
  const int rl = l >> 2;        // row within wave's 16
  const int cs = l & 3;         // col-seg

#pragma unroll
  for (int c = 0; c < 16; ++c){
    // ledger: pre D0 B0 D1; iter c issues B(c+1), S(c), D(c+2).
    // c=0: [D0,B0,D1]=12 -> vmcnt(4); 1<=c<=14: retire {S(c-2),D(c),B(c)} -> vmcnt(8);
    // c=15: [S13,D15,B15,S14]=16 -> vmcnt(4).
    if (c == 0 || c == 15) asm volatile("s_waitcnt vmcnt(4)" ::: "memory");
    else                   asm volatile("s_waitcnt vmcnt(8)" ::: "memory");
    __builtin_amdgcn_sched_barrier(0);
    {
      f32x4 d0 = __builtin_amdgcn_mfma_f32_16x16x32_bf16(aV, bwc0, z4, 0, 0, 0);
      f32x4 d1 = __builtin_amdgcn_mfma_f32_16x16x32_bf16(aV, bwc1, z4, 0, 0, 0);
      f32x4 d2 = __builtin_amdgcn_mfma_f32_16x16x32_bf16(aV, bwc2, z4, 0, 0, 0);
      f32x4 d3 = __builtin_amdgcn_mfma_f32_16x16x32_bf16(aV, bwc3, z4, 0, 0, 0);
#pragma unroll
      for (int r = 0; r < 4; ++r){
        int rowb = (kg*4 + r)*68;
        Cw[rowb +  0 + ln16] = d0[r];
        Cw[rowb + 16 + ln16] = d1[r];
        Cw[rowb + 32 + ln16] = d2[r];
        Cw[rowb + 48 + ln16] = d3[r];
      }
    }
    __builtin_amdgcn_sched_barrier(0);
    // next bw frags (issued before this chunk's stores)
    bf16x8 bwn0 = bwc0, bwn1 = bwc1, bwn2 = bwc2, bwn3 = bwc3;
    if (c < 15 && kg < 3){
      bwn0 = *reinterpret_cast<const bf16x8*>(&wsFC[((c+1)*4+0)*384 + l*8]);
      bwn1 = *reinterpret_cast<const bf16x8*>(&wsFC[((c+1)*4+1)*384 + l*8]);
      bwn2 = *reinterpret_cast<const bf16x8*>(&wsFC[((c+1)*4+2)*384 + l*8]);
      bwn3 = *reinterpret_cast<const bf16x8*>(&wsFC[((c+1)*4+3)*384 + l*8]);
    }
    __builtin_amdgcn_sched_barrier(0);
    asm volatile("s_waitcnt lgkmcnt(0)" ::: "memory");
    __builtin_amdgcn_sched_barrier(0);
    // residual pass: wave-local rows, 64B-run coalesced L2-merged stores
#pragma unroll
    for (int q = 0; q < 4; ++q){
      int bi = cs + 4*q;
      f32x4 xv = *reinterpret_cast<const f32x4*>(
          W + (c & 1)*4096 + rl*256 + ((bi ^ (rl & 7)))*16);
      f32x4 cv = *reinterpret_cast<const f32x4*>(&Cw[rl*68 + bi*4]);
      f32x4 ov = xv + cv;
      *reinterpret_cast<f32x4*>(&out[(size_t)(tokBase + rl)*DM + c*64 + bi*4]) = ov;
    }
    __builtin_amdgcn_sched_barrier(0);
    if (c < 14){                      // D(c+2) -> buf c&1 (its reads are done)
#pragma unroll
      for (int j = 0; j < 4; ++j){
        int lr = j*4 + (l >> 4);
        gl_lds16(x + (size_t)(tokBase + lr)*DM + (c+2)*64 + ((l & 15) ^ (lr & 7))*4,
                 W + (c & 1)*4096 + j*1024 + l*16);
      }
    }
    bwc0 = bwn0; bwc1 = bwn1; bwc2 = bwn2; bwc3 = bwn3;
  }

  // gate sums -> spread ws slots (after all counted waits)
  if (l == 48){
    float* slot = wsA + ((blockIdx.x*4 + wv) & (NSLOT-1))*16;
    atomicAdd(slot + 0, sg0);
    atomicAdd(slot + 1, sg1);
    atomicAdd(slot + 2, sg2);
  }
}

// ---------------- finalize: reduce 32 gate slots -> out[OUT_OFF..+2] --------
__global__ void finalize_kernel(const float* __restrict__ wsA, float* __restrict__ out){
  if (threadIdx.x < 3){
    float s = 0.f;
    for (int j = 0; j < NSLOT; ++j) s += wsA[j*16 + threadIdx.x];
    out[OUT_OFF + threadIdx.x] = s * (1.f / (float)NTOK);
  }
}

extern "C" void kernel_launch(void* const* d_in, const int* in_sizes, int n_in,
                              void* d_out, int out_size, void* d_ws, size_t ws_size,
                              hipStream_t stream){
  (void)in_sizes; (void)n_in; (void)ws_size; (void)out_size;
  const float* x         = (const float*)d_in[0];
  // d_in[1] (codes_l1), d_in[2] (codes_l2) unused: corners derived from bits
  const float* w_to_l1   = (const float*)d_in[3];
  const float* w_from_l1 = (const float*)d_in[4];
  const float* w_to_l2   = (const float*)d_in[5];
  const float* w_from_l2 = (const float*)d_in[6];
  const float* w_to_l3u  = (const float*)d_in[7];
  const float* w_to_l3l  = (const float*)d_in[8];
  const float* w_from_l3 = (const float*)d_in[9];
  const float* w_gate    = (const float*)d_in[10];
  const float* b_gate    = (const float*)d_in[11];
  const float* t1 = (const float*)d_in[12];
  const float* t2 = (const float*)d_in[13];
  const float* t3 = (const float*)d_in[14];
  const float* s1 = (const float*)d_in[15];
  const float* s2 = (const float*)d_in[16];
  const float* s3 = (const float*)d_in[17];
  float* out  = (float*)d_out;
  short* wsF  = (short*)d_ws;                       // 57344 shorts of fragments
  float* wsA  = (float*)d_ws + WSA_OFF;             // 32 slots x 16 floats

  pack_kernel<<<dim3(14), dim3(256), 0, stream>>>(
      w_to_l1, w_to_l2, w_to_l3u, w_to_l3l, w_gate,
      w_from_l1, w_from_l2, w_from_l3, wsF, wsA);
  hq8_kernel<<<dim3(512), dim3(256), 0, stream>>>(
      x, wsF, b_gate, t1, t2, t3, s1, s2, s3, wsA, out);
  finalize_kernel<<<dim3(1), dim3(64), 0, stream>>>(wsA, out);
}